// Round 2
// baseline (164.055 us; speedup 1.0000x reference)
//
#include <hip/hip_runtime.h>
#include <hip/hip_bf16.h>

#define DDIM 256
#define NROWS 8192

typedef __attribute__((ext_vector_type(8))) __bf16 bf16x8;
typedef __attribute__((ext_vector_type(4))) float floatx4;

// async global->LDS, 16B per lane. LDS dest is wave-uniform base + lane*16.
__device__ __forceinline__ void async16(const void* g, void* l) {
    __builtin_amdgcn_global_load_lds(
        (const __attribute__((address_space(1))) unsigned int*)g,
        (__attribute__((address_space(3))) unsigned int*)l,
        16, 0, 0);
}

// Kernel 1: L2-normalize rows of U and P to bf16, compute pos_sim, zero the
// rowsum accumulator and the output scalar. One wave per row.
__global__ __launch_bounds__(256) void normalize_kernel(
    const float* __restrict__ U, const float* __restrict__ P,
    unsigned short* __restrict__ Un, unsigned short* __restrict__ Pn,
    float* __restrict__ possim, float* __restrict__ rowsum,
    float* __restrict__ out)
{
    if (blockIdx.x == 0 && threadIdx.x == 0) out[0] = 0.0f;
    const int lane = threadIdx.x & 63;
    const int row  = blockIdx.x * 4 + (threadIdx.x >> 6);
    const size_t base = (size_t)row * DDIM + lane * 4;
    const float4 u4 = *(const float4*)(U + base);
    const float4 p4 = *(const float4*)(P + base);
    float su = u4.x*u4.x + u4.y*u4.y + u4.z*u4.z + u4.w*u4.w;
    float sp = p4.x*p4.x + p4.y*p4.y + p4.z*p4.z + p4.w*p4.w;
    float up = u4.x*p4.x + u4.y*p4.y + u4.z*p4.z + u4.w*p4.w;
    #pragma unroll
    for (int d = 1; d < 64; d <<= 1) {
        su += __shfl_xor(su, d);
        sp += __shfl_xor(sp, d);
        up += __shfl_xor(up, d);
    }
    const float iu = rsqrtf(fmaxf(su, 1e-24f));
    const float ip = rsqrtf(fmaxf(sp, 1e-24f));
    if (lane == 0) {
        possim[row] = up * iu * ip;
        rowsum[row] = 0.0f;
    }
    union { ushort4 s4; __hip_bfloat16 h[4]; } cu, cp;
    cu.h[0] = __float2bfloat16(u4.x * iu); cu.h[1] = __float2bfloat16(u4.y * iu);
    cu.h[2] = __float2bfloat16(u4.z * iu); cu.h[3] = __float2bfloat16(u4.w * iu);
    cp.h[0] = __float2bfloat16(p4.x * ip); cp.h[1] = __float2bfloat16(p4.y * ip);
    cp.h[2] = __float2bfloat16(p4.z * ip); cp.h[3] = __float2bfloat16(p4.w * ip);
    *(ushort4*)(Un + base) = cu.s4;
    *(ushort4*)(Pn + base) = cp.s4;
}

// Kernel 2: one 256x128 tile of sim = Un * Pn^T per block (doubled M vs R1 to
// double MFMA work per barrier/drain). 4 waves in 2x2; wave-tile 128x64 =
// 8x4 MFMA 16x16x32 tiles (acc = 128 VGPR). K=256 in 4 chunks of BK=64.
// LDS 48 KB (A 256x64 + B 128x64), single-buffered -> 2 blocks/CU overlap.
// Swizzle: granule ^ (row&7) keeps staging contiguous and ds_read_b128
// 2-way-aliased only (free per m136; R1 measured 0 conflicts).
__global__ __launch_bounds__(256, 2) void sim_exp_rowsum(
    const unsigned short* __restrict__ Un,
    const unsigned short* __restrict__ Pn,
    float* __restrict__ rowsum)
{
    __shared__ __align__(16) unsigned short As[256 * 64];   // 32 KB
    __shared__ __align__(16) unsigned short Bs[128 * 64];   // 16 KB
    const int tid  = threadIdx.x;
    const int lane = tid & 63;
    const int wv   = tid >> 6;
    const int wr   = wv >> 1, wc = wv & 1;
    const int rowblock = blockIdx.y, colblock = blockIdx.x;

    floatx4 acc[8][4];
    #pragma unroll
    for (int t = 0; t < 8; ++t)
        #pragma unroll
        for (int u = 0; u < 4; ++u)
            acc[t][u] = {0.0f, 0.0f, 0.0f, 0.0f};

    const int srow = lane >> 3;            // row within an 8-row staging group
    const int gg   = (lane & 7) ^ srow;    // swizzled global granule to fetch
    const size_t abase = (size_t)rowblock * 256 * DDIM;
    const size_t bbase = (size_t)colblock * 128 * DDIM;
    const int q = lane >> 4;               // quad
    const int m = lane & 15;

    #pragma unroll
    for (int kc = 0; kc < 4; ++kc) {
        const int k0 = kc * 64;
        __syncthreads();   // all waves done reading previous chunk
        #pragma unroll
        for (int i = 0; i < 8; ++i) {      // A: 32 row-groups / 4 waves
            const int rg = wv * 8 + i;
            const int r  = rg * 8 + srow;
            async16(Un + abase + (size_t)r * DDIM + k0 + gg * 8, &As[rg * 8 * 64]);
        }
        #pragma unroll
        for (int i = 0; i < 4; ++i) {      // B: 16 row-groups / 4 waves
            const int rg = wv * 4 + i;
            const int r  = rg * 8 + srow;
            async16(Pn + bbase + (size_t)r * DDIM + k0 + gg * 8, &Bs[rg * 8 * 64]);
        }
        __syncthreads();   // vmcnt(0) drain + barrier: staging visible
        #pragma unroll
        for (int ks = 0; ks < 2; ++ks) {
            bf16x8 af[8], bfr[4];
            const int gl = ks * 4 + q;                 // logical k-granule 0..7
            const int gp = (gl ^ (m & 7)) * 8;         // swizzled LDS offset
            #pragma unroll
            for (int t = 0; t < 8; ++t)
                af[t]  = *(const bf16x8*)&As[(wr * 128 + t * 16 + m) * 64 + gp];
            #pragma unroll
            for (int u = 0; u < 4; ++u)
                bfr[u] = *(const bf16x8*)&Bs[(wc * 64 + u * 16 + m) * 64 + gp];
            #pragma unroll
            for (int t = 0; t < 8; ++t)
                #pragma unroll
                for (int u = 0; u < 4; ++u)
                    acc[t][u] = __builtin_amdgcn_mfma_f32_16x16x32_bf16(
                        af[t], bfr[u], acc[t][u], 0, 0, 0);
        }
    }

    // Epilogue: C/D layout col = lane&15, row = (lane>>4)*4 + reg.
    // exp(5*dot); sum this wave's 64 columns (4 in-lane + 16-lane shuffle),
    // one atomicAdd per row per wave.
    #pragma unroll
    for (int t = 0; t < 8; ++t) {
        #pragma unroll
        for (int r = 0; r < 4; ++r) {
            float s = __expf(5.0f * acc[t][0][r]) + __expf(5.0f * acc[t][1][r])
                    + __expf(5.0f * acc[t][2][r]) + __expf(5.0f * acc[t][3][r]);
            s += __shfl_xor(s, 1);
            s += __shfl_xor(s, 2);
            s += __shfl_xor(s, 4);
            s += __shfl_xor(s, 8);
            if (m == 0) {
                const int grow = rowblock * 256 + wr * 128 + t * 16 + q * 4 + r;
                atomicAdd(&rowsum[grow], s);
            }
        }
    }
}

// Kernel 3: loss = mean_i( log(rowsum_i) - 5 * possim_i ). 32 blocks, one
// element per thread, block-reduce, atomicAdd into out (zeroed by kernel 1).
__global__ __launch_bounds__(256) void finalize_kernel(
    const float* __restrict__ rowsum, const float* __restrict__ possim,
    float* __restrict__ out)
{
    const int i = blockIdx.x * 256 + threadIdx.x;
    float acc = __logf(rowsum[i]) - 5.0f * possim[i];
    #pragma unroll
    for (int d = 1; d < 64; d <<= 1) acc += __shfl_xor(acc, d);
    __shared__ float wsum[4];
    if ((threadIdx.x & 63) == 0) wsum[threadIdx.x >> 6] = acc;
    __syncthreads();
    if (threadIdx.x == 0)
        atomicAdd(out, (wsum[0] + wsum[1] + wsum[2] + wsum[3]) * (1.0f / (float)NROWS));
}

extern "C" void kernel_launch(void* const* d_in, const int* in_sizes, int n_in,
                              void* d_out, int out_size, void* d_ws, size_t ws_size,
                              hipStream_t stream) {
    const float* U = (const float*)d_in[0];
    const float* P = (const float*)d_in[1];
    float* out = (float*)d_out;
    char* ws = (char*)d_ws;
    // ws layout: Un bf16 (4 MB) | Pn bf16 (4 MB) | rowsum f32 (32 KB) | possim f32 (32 KB)
    unsigned short* Un = (unsigned short*)ws;
    unsigned short* Pn = (unsigned short*)(ws + 4194304);
    float* rowsum = (float*)(ws + 8388608);
    float* possim = (float*)(ws + 8388608 + 32768);

    normalize_kernel<<<NROWS / 4, 256, 0, stream>>>(U, P, Un, Pn, possim, rowsum, out);
    dim3 g2(64, 32);   // x = col tile (128 wide), y = row tile (256 tall)
    sim_exp_rowsum<<<g2, 256, 0, stream>>>(Un, Pn, rowsum);
    finalize_kernel<<<NROWS / 256, 256, 0, stream>>>(rowsum, possim, out);
}